// Round 6
// baseline (8625.220 us; speedup 1.0000x reference)
//
#include <hip/hip_runtime.h>

typedef unsigned short u16;
typedef unsigned int u32;
typedef unsigned long long u64;
typedef __attribute__((ext_vector_type(8))) short bf16x8;
typedef __attribute__((ext_vector_type(4))) float f32x4;
typedef __attribute__((ext_vector_type(4))) unsigned short us4;

#define MFMA(a,b,c) __builtin_amdgcn_mfma_f32_16x16x32_bf16((a),(b),(c),0,0,0)
#define KEEP(x) asm volatile("" : "+v"(x))

// B=128, SEQ=200, VOCAB=1400 (pad 1408), D=H=256, 4H=1024, NCLS=128, M=B*SEQ=25600

static __device__ __forceinline__ u16 f2b(float f){
  unsigned u = __float_as_uint(f);
  u += 0x7fffu + ((u >> 16) & 1u);          // RNE fp32 -> bf16
  return (u16)(u >> 16);
}
static __device__ __forceinline__ float sigm(float x){ return 1.0f/(1.0f+__expf(-x)); }
static __device__ __forceinline__ float tanhx(float x){
  x = fminf(fmaxf(x, -15.f), 15.f);
  float e = __expf(-2.f*x);
  return (1.f - e)/(1.f + e);
}
static __device__ __forceinline__ void gl16(const void* g, void* l){
  __builtin_amdgcn_global_load_lds((const __attribute__((address_space(1))) void*)g,
                                   (__attribute__((address_space(3))) void*)l, 16, 0, 0);
}

// ---------------- fused prep: inputs cvt + emb transpose-cvt + weights ----
__global__ __launch_bounds__(256) void k_prep(
  const float* __restrict__ in0, u16* __restrict__ A0,
  const float* __restrict__ emb, u16* __restrict__ embT,
  const float* __restrict__ s0, const float* __restrict__ s1, const float* __restrict__ s2,
  const float* __restrict__ s3, const float* __restrict__ s4, const float* __restrict__ s5,
  const float* __restrict__ s6,
  u16* __restrict__ d0, u16* __restrict__ d1, u16* __restrict__ d2, u16* __restrict__ d3,
  u16* __restrict__ d4, u16* __restrict__ d5, u16* __restrict__ d6)
{
  int bx = blockIdx.x, tid = threadIdx.x;
  if (bx < 35200){                     // inputs [25600 x 1400] -> bf16 padded 1408
    long long i4 = (long long)bx*256 + tid;      // < 9011200 exactly
    long long o = i4*4;
    int r = (int)(o / 1408);
    int c = (int)(o % 1408);
    us4 d;
    if (c + 4 <= 1400){
      f32x4 v = *(const f32x4*)&in0[(long long)r*1400 + c];
      d[0]=f2b(v[0]); d[1]=f2b(v[1]); d[2]=f2b(v[2]); d[3]=f2b(v[3]);
    } else {
      for (int k=0;k<4;k++){ int cc=c+k; d[k] = (cc<1400)? f2b(in0[(long long)r*1400+cc]) : (u16)0; }
    }
    *(us4*)&A0[(long long)r*1408 + c] = d;
  } else if (bx < 36608){              // emb [1400x256] -> embT [256x1408] bf16
    int idx = (bx-35200)*256 + tid;    // < 360448 exactly
    int n = idx / 1408, k = idx % 1408;
    embT[idx] = (k < 1400) ? f2b(emb[(long long)k*256 + n]) : (u16)0;
  } else {                             // 7 weight arrays fp32 -> bf16
    long long q = (long long)(bx-36608)*256 + tid;   // < 311296 exactly
    const float* src; u16* dst; long long rel;
    if      (q < 65536)  { src=s0; dst=d0; rel=q; }
    else if (q < 131072) { src=s1; dst=d1; rel=q-65536; }
    else if (q < 196608) { src=s2; dst=d2; rel=q-131072; }
    else if (q < 262144) { src=s3; dst=d3; rel=q-196608; }
    else if (q < 278528) { src=s4; dst=d4; rel=q-262144; }
    else if (q < 294912) { src=s5; dst=d5; rel=q-278528; }
    else                 { src=s6; dst=d6; rel=q-294912; }
    long long o = rel*4;
    f32x4 v = *(const f32x4*)&src[o];
    us4 d; d[0]=f2b(v[0]); d[1]=f2b(v[1]); d[2]=f2b(v[2]); d[3]=f2b(v[3]);
    *(us4*)&dst[o] = d;
  }
}

// ---------------- weight repack for streamed scan -------------------------
// wpk fragment id = (((lstm*4 + w)*8 + kk)*20 + tau)*64 + l  (16B each).
// tau 0..15: gate rows  (g=tau>>2, j = w*64 + (tau&3)*16 + lb)
// tau 16..19: Wd rows   (j = w*64 + (tau-16)*16 + lb)
// lane l: quad=l>>4 gives k-slice quad*8 within kk*32; lb=l&15 gives row.
// This matches the proven A-frag pattern Wall[row*256 + kk*32 + quad*8].
__global__ __launch_bounds__(256) void k_wpack(
  const u16* __restrict__ Wall1, const u16* __restrict__ Wd1,
  const u16* __restrict__ Wall2, const u16* __restrict__ Wd2,
  u16* __restrict__ wpk)
{
  int id = blockIdx.x*256 + threadIdx.x;   // 320*256 = 81920 exactly
  int l = id & 63, f = id >> 6;            // f 0..1279
  int tau = f % 20;
  int kk  = (f/20) & 7;
  int w   = (f/160) & 3;
  int lstm= f / 640;
  int quad = l >> 4, lb = l & 15;
  const u16* Wall = lstm ? Wall2 : Wall1;
  const u16* Wd   = lstm ? Wd2   : Wd1;
  const u16* src;
  if (tau < 16){
    int row = (tau>>2)*256 + w*64 + (tau&3)*16 + lb;
    src = &Wall[(long long)row*256 + kk*32 + quad*8];
  } else {
    int row = w*64 + (tau-16)*16 + lb;
    src = &Wd[(long long)row*256 + kk*32 + quad*8];
  }
  *(bf16x8*)&wpk[(long long)id*8] = *(const bf16x8*)src;
}

// ---------------- init: zero ctx (atomic accumulation target) -------------
__global__ __launch_bounds__(256) void k_init(float* __restrict__ ctx){
  int i = blockIdx.x*256 + threadIdx.x;     // 128*256 = 32768 exactly
  ctx[i] = 0.f;
}

// ---------------- bf16 MFMA GEMM: C[M,N] = A[M,K] * Bt[N,K]^T -------------
// EPI 1: write fp32 + bf16 copies
// EPI 4: dual-output ux GEMM, +bias pair, fp32 (blockIdx.y>=8 -> second set)
// EPI 5: ctx[b,col] += emb[row,col]*tanh(acc)*alpha[row]  (LDS + global atomics)
template<int EPI>
__global__ __launch_bounds__(256) void k_gemm(const u16* __restrict__ A, const u16* __restrict__ Bt,
    int N, int K,
    float* __restrict__ Cf, u16* __restrict__ Cb,
    const float* __restrict__ bias1, const float* __restrict__ bias2,
    const u16* __restrict__ Bt2, float* __restrict__ Cf2,
    const float* __restrict__ bias3, const float* __restrict__ bias4,
    const float* __restrict__ emb, const float* __restrict__ alpha)
{
  __shared__ __align__(16) u16 As[128*64];
  __shared__ __align__(16) u16 Bs[128*64];
  __shared__ float red[2][128];
  const int tid = threadIdx.x;
  const int l = tid & 63, w = tid >> 6;
  const int quad = l >> 4, lb = l & 15;
  const int wr = w >> 1, wc = w & 1;
  const long long m0 = (long long)blockIdx.x * 128;
  int n0 = blockIdx.y * 128;
  if (EPI==4 && blockIdx.y >= 8){
    Bt = Bt2; Cf = Cf2; bias1 = bias3; bias2 = bias4; n0 = (blockIdx.y-8)*128;
  }

  f32x4 acc[4][4];
  #pragma unroll
  for (int i=0;i<4;i++)
    #pragma unroll
    for (int j=0;j<4;j++) acc[i][j] = (f32x4){0.f,0.f,0.f,0.f};

  for (int kk = 0; kk < K; kk += 64){
    #pragma unroll
    for (int it=0; it<4; ++it){      // 128x64 bf16 tile, XOR-swizzled 16B slots
      int slot = it*256 + tid;
      int m = slot >> 3;
      int q = (slot & 7) ^ (m & 7);
      gl16(A + (m0+m)*K + kk + q*8, &As[slot*8]);
    }
    #pragma unroll
    for (int it=0; it<4; ++it){
      int slot = it*256 + tid;
      int m = slot >> 3;
      int q = (slot & 7) ^ (m & 7);
      gl16(Bt + (long long)(n0+m)*K + kk + q*8, &Bs[slot*8]);
    }
    __syncthreads();
    #pragma unroll
    for (int ks=0; ks<2; ++ks){
      int kq = quad + ks*4;
      bf16x8 af[4], bfr[4];
      #pragma unroll
      for (int i=0;i<4;i++){ int m = wr*64 + i*16 + lb; af[i]  = *(const bf16x8*)&As[m*64 + ((kq ^ (m&7))*8)]; }
      #pragma unroll
      for (int j=0;j<4;j++){ int n = wc*64 + j*16 + lb; bfr[j] = *(const bf16x8*)&Bs[n*64 + ((kq ^ (n&7))*8)]; }
      #pragma unroll
      for (int i=0;i<4;i++)
        #pragma unroll
        for (int j=0;j<4;j++)
          acc[i][j] = MFMA(af[i], bfr[j], acc[i][j]);
    }
    __syncthreads();
  }

  if (EPI==5){
    const int b0 = (int)(m0 / 200);
    red[tid>>7][tid&127] = 0.f;
    __syncthreads();
    #pragma unroll
    for (int i=0;i<4;i++){
      #pragma unroll
      for (int j=0;j<4;j++){
        int col = wc*64 + j*16 + lb;          // 0..127 within n0 tile
        #pragma unroll
        for (int r=0;r<4;r++){
          long long row = m0 + wr*64 + i*16 + quad*4 + r;
          long long o = row*N + n0 + col;
          float v = emb[o] * tanhx(acc[i][j][r]) * alpha[row];
          atomicAdd(&red[(int)(row/200) - b0][col], v);
        }
      }
    }
    __syncthreads();
    int bl = tid >> 7, col = tid & 127;       // 256 threads cover [2][128]
    int bb = b0 + bl;
    if (bb < 128) atomicAdd(&Cf[bb*256 + n0 + col], red[bl][col]);
    return;
  }

  #pragma unroll
  for (int i=0;i<4;i++){
    #pragma unroll
    for (int j=0;j<4;j++){
      int col = n0 + wc*64 + j*16 + lb;
      #pragma unroll
      for (int r=0;r<4;r++){
        long long row = m0 + wr*64 + i*16 + quad*4 + r;
        long long o = row*N + col;
        float v = acc[i][j][r];
        if (EPI==1){ Cf[o]=v; Cb[o]=f2b(v); }
        else { Cf[o] = v + bias1[col] + bias2[col]; }   // EPI 4
      }
    }
  }
}

// ---------------- TimeLSTM scan: batch-split, ZERO cross-WG sync ----------
// 8 WGs: lstm = bi&1, bc = bi>>1 (32 batches each, 2 MFMA batch-tiles).
// Each WG owns the FULL j=256 h/c state for its 32 batches in LDS; nothing
// is exchanged between WGs. One WG per XCD under round-robin => each XCD's
// L2 holds its lstm's 640KB packed weights after step 0.
//
// r5 lesson: per-fragment load->MFMA serialized into 160 L2 round trips
// (43k cy/step). Fix: (a) per kk-step, load ALL 20 fragments into a register
// array in a separate loop (KEEP-pinned) so the wave issues 20 independent
// 16B loads back-to-back — one L2 latency amortized over 20 loads + 40
// MFMAs; (b) each fragment now feeds 2 MFMAs (2 batch-tiles) halving
// per-batch weight traffic; (c) __launch_bounds__(256,1) => 512-VGPR budget
// (~350 live) so the scheduler can hoist kk+1 loads over kk MFMAs.
// ux consumed at elementwise (r5-proven numerics), one batched 32-load wait.
// E written as per-wave partials E4[w][b][s] (plain stores, no atomics).
__global__ __launch_bounds__(256,1) void k_scan(
  const u16* __restrict__ wpk,
  const float* __restrict__ Wd1b, const float* __restrict__ ux1,
  const float* __restrict__ h01, const float* __restrict__ c01,
  const float* __restrict__ Wd2b, const float* __restrict__ ux2,
  const float* __restrict__ h02, const float* __restrict__ c02,
  const float* __restrict__ ts, const float* __restrict__ wa,
  float* __restrict__ E4, u16* __restrict__ out2)
{
  __shared__ __align__(16) u16 hb[32][264];
  __shared__ __align__(16) u16 cb[32][264];
  const int bi = blockIdx.x;
  const int lstm = bi & 1;
  const int bc   = bi >> 1;            // 0..3, batches [bc*32, bc*32+32)
  const float* Wdb = lstm ? Wd2b : Wd1b;
  const float* ux  = lstm ? ux2  : ux1;
  const float* h0  = lstm ? h02  : h01;
  const float* c0  = lstm ? c02  : c01;

  const int tid = threadIdx.x;
  const int l = tid & 63, w = tid >> 6;
  const int quad = l >> 4, lb = l & 15;
  const int bg0 = bc*32 + lb;           // tile-0 batch
  const int bg1 = bc*32 + 16 + lb;      // tile-1 batch
  const int jb = w*64 + quad*4;         // lane's base j; tile jt adds jt*16

  const u16* wp = wpk + (long long)(lstm*4 + w)*81920 + l*8;  // this wave's frags

  // per-lane constants (j-dependent only — shared by both batch-tiles)
  f32x4 bcs4[4], wav4[4], creg0[4], creg1[4];
  #pragma unroll
  for (int jt=0; jt<4; ++jt){
    bcs4[jt]  = *(const f32x4*)&Wdb[jb + jt*16];
    wav4[jt]  = *(const f32x4*)&wa[jb + jt*16];
    creg0[jt] = *(const f32x4*)&c0[(long long)bg0*256 + jb + jt*16];
    creg1[jt] = *(const f32x4*)&c0[(long long)bg1*256 + jb + jt*16];
  }

  // init LDS h/c (32 batches x full 256 j), bf16
  {
    const int row = tid >> 3, j0i = (tid & 7) * 32;
    #pragma unroll
    for (int kq=0; kq<8; ++kq){
      f32x4 hv = *(const f32x4*)&h0[(long long)(bc*32+row)*256 + j0i + kq*4];
      f32x4 cv = *(const f32x4*)&c0[(long long)(bc*32+row)*256 + j0i + kq*4];
      us4 hp0, cp0;
      #pragma unroll
      for (int r=0;r<4;++r){ hp0[r]=f2b(hv[r]); cp0[r]=f2b(cv[r]); }
      *(us4*)&hb[row][j0i+kq*4] = hp0;
      *(us4*)&cb[row][j0i+kq*4] = cp0;
    }
  }
  __syncthreads();

  for (int s=0; s<200; ++s){
    // acc init (gates zero — ux added at elementwise; Wd rows get bias)
    f32x4 acc0[20], acc1[20];
    #pragma unroll
    for (int t=0; t<16; ++t){ acc0[t] = (f32x4){0.f,0.f,0.f,0.f}; acc1[t] = (f32x4){0.f,0.f,0.f,0.f}; }
    #pragma unroll
    for (int jt=0; jt<4; ++jt){ acc0[16+jt] = bcs4[jt]; acc1[16+jt] = bcs4[jt]; }

    // GEMV: 8 k-steps; per kk load 20 fragments BATCHED, then 40 MFMAs
    #pragma unroll
    for (int kk=0; kk<8; ++kk){
      const u16* wk = wp + kk*10240;
      bf16x8 wbuf[20];
      #pragma unroll
      for (int t=0; t<20; ++t){ wbuf[t] = *(const bf16x8*)&wk[t*512]; KEEP(wbuf[t]); }
      bf16x8 hf0 = *(const bf16x8*)&hb[lb][kk*32 + quad*8];
      bf16x8 hf1 = *(const bf16x8*)&hb[16+lb][kk*32 + quad*8];
      bf16x8 cf0 = *(const bf16x8*)&cb[lb][kk*32 + quad*8];
      bf16x8 cf1 = *(const bf16x8*)&cb[16+lb][kk*32 + quad*8];
      #pragma unroll
      for (int t=0; t<16; ++t){
        acc0[t] = MFMA(wbuf[t], hf0, acc0[t]);
        acc1[t] = MFMA(wbuf[t], hf1, acc1[t]);
      }
      #pragma unroll
      for (int jt=0; jt<4; ++jt){
        acc0[16+jt] = MFMA(wbuf[16+jt], cf0, acc0[16+jt]);
        acc1[16+jt] = MFMA(wbuf[16+jt], cf1, acc1[16+jt]);
      }
    }

    // elementwise per batch-tile (ux loaded batched here; weights regs dead)
    us4 hp0[4], cp0[4], hp1[4], cp1[4];
    {
      f32x4 uxv[16];
      #pragma unroll
      for (int g=0; g<4; ++g)
        #pragma unroll
        for (int jt=0; jt<4; ++jt)
          uxv[g*4+jt] = *(const f32x4*)&ux[((long long)bg0*200 + s)*1024 + g*256 + jb + jt*16];
      float tcur = ts[(long long)bg0*200 + s];
      f32x4 hn4[4];
      #pragma unroll
      for (int jt=0; jt<4; ++jt){
        #pragma unroll
        for (int r=0; r<4; ++r){
          float cs1 = tanhx(acc0[16+jt][r]);
          float cadj = creg0[jt][r] + cs1*(tcur - 1.0f);
          float fg = sigm(acc0[0*4+jt][r] + uxv[0*4+jt][r]);
          float ig = sigm(acc0[1*4+jt][r] + uxv[1*4+jt][r]);
          float og = sigm(acc0[2*4+jt][r] + uxv[2*4+jt][r]);
          float cg = sigm(acc0[3*4+jt][r] + uxv[3*4+jt][r]);
          float cn = fg*cadj + ig*cg;
          float hv = og*tanhx(cn);
          creg0[jt][r]=cn; hn4[jt][r]=hv;
          hp0[jt][r]=f2b(hv); cp0[jt][r]=f2b(cn);
        }
      }
      if (lstm==0){
        float e = 0.f;
        #pragma unroll
        for (int jt=0; jt<4; ++jt)
          #pragma unroll
          for (int r=0; r<4; ++r) e += hn4[jt][r]*wav4[jt][r];
        e += __shfl_xor(e, 16, 64);
        e += __shfl_xor(e, 32, 64);
        if (l < 16) E4[((long long)w*128 + bg0)*200 + s] = e;
      } else {
        #pragma unroll
        for (int jt=0; jt<4; ++jt)
          *(us4*)&out2[((long long)bg0*200 + s)*256 + jb + jt*16] = hp0[jt];
      }
    }
    {
      f32x4 uxv[16];
      #pragma unroll
      for (int g=0; g<4; ++g)
        #pragma unroll
        for (int jt=0; jt<4; ++jt)
          uxv[g*4+jt] = *(const f32x4*)&ux[((long long)bg1*200 + s)*1024 + g*256 + jb + jt*16];
      float tcur = ts[(long long)bg1*200 + s];
      f32x4 hn4[4];
      #pragma unroll
      for (int jt=0; jt<4; ++jt){
        #pragma unroll
        for (int r=0; r<4; ++r){
          float cs1 = tanhx(acc1[16+jt][r]);
          float cadj = creg1[jt][r] + cs1*(tcur - 1.0f);
          float fg = sigm(acc1[0*4+jt][r] + uxv[0*4+jt][r]);
          float ig = sigm(acc1[1*4+jt][r] + uxv[1*4+jt][r]);
          float og = sigm(acc1[2*4+jt][r] + uxv[2*4+jt][r]);
          float cg = sigm(acc1[3*4+jt][r] + uxv[3*4+jt][r]);
          float cn = fg*cadj + ig*cg;
          float hv = og*tanhx(cn);
          creg1[jt][r]=cn; hn4[jt][r]=hv;
          hp1[jt][r]=f2b(hv); cp1[jt][r]=f2b(cn);
        }
      }
      if (lstm==0){
        float e = 0.f;
        #pragma unroll
        for (int jt=0; jt<4; ++jt)
          #pragma unroll
          for (int r=0; r<4; ++r) e += hn4[jt][r]*wav4[jt][r];
        e += __shfl_xor(e, 16, 64);
        e += __shfl_xor(e, 32, 64);
        if (l < 16) E4[((long long)w*128 + bg1)*200 + s] = e;
      } else {
        #pragma unroll
        for (int jt=0; jt<4; ++jt)
          *(us4*)&out2[((long long)bg1*200 + s)*256 + jb + jt*16] = hp1[jt];
      }
    }

    // LDS h/c update (intra-CU only; raw barriers, no vmcnt drain)
    if (s < 199){
      asm volatile("" ::: "memory");
      __builtin_amdgcn_s_barrier();            // B1: all GEMV LDS reads done
      asm volatile("" ::: "memory");
      #pragma unroll
      for (int jt=0; jt<4; ++jt){
        *(us4*)&hb[lb][jb + jt*16]    = hp0[jt];
        *(us4*)&cb[lb][jb + jt*16]    = cp0[jt];
        *(us4*)&hb[16+lb][jb + jt*16] = hp1[jt];
        *(us4*)&cb[16+lb][jb + jt*16] = cp1[jt];
      }
      asm volatile("s_waitcnt lgkmcnt(0)" ::: "memory");
      __builtin_amdgcn_sched_barrier(0);
      __builtin_amdgcn_s_barrier();            // B2: h/c(s+1) visible
      asm volatile("" ::: "memory");
    }
  }
}

// ---------------- softmax over E4 partials -> alpha ----------------
__global__ __launch_bounds__(256) void k_attn(const float* __restrict__ E4, float* __restrict__ alpha){
  __shared__ float buf[256];
  int b = blockIdx.x, tid = threadIdx.x;
  float Ev = -1e30f;
  if (tid < 200){
    long long o = (long long)b*200 + tid;
    Ev = E4[o] + E4[25600 + o] + E4[51200 + o] + E4[76800 + o];
  }
  buf[tid]=Ev; __syncthreads();
  for (int st=128; st>0; st>>=1){ if (tid<st) buf[tid]=fmaxf(buf[tid],buf[tid+st]); __syncthreads(); }
  float mx = buf[0]; __syncthreads();
  float e = (tid<200)? __expf(Ev-mx) : 0.f;
  buf[tid]=e; __syncthreads();
  for (int st=128; st>0; st>>=1){ if (tid<st) buf[tid]+=buf[tid+st]; __syncthreads(); }
  float sm = buf[0];
  if (tid<200) alpha[(long long)b*200+tid] = e/sm;
}

// ---------------- out = ctx @ Wout^T ----------------
__global__ __launch_bounds__(128) void k_out(const float* __restrict__ ctx, const float* __restrict__ Wout,
                                             float* __restrict__ out){
  __shared__ float cs[256];
  int b = blockIdx.x, t = threadIdx.x;
  cs[t] = ctx[b*256+t]; cs[t+128] = ctx[b*256+t+128];
  __syncthreads();
  const float* wr = Wout + (long long)t*256;
  float a0=0,a1=0,a2=0,a3=0;
  for (int j=0;j<256;j+=4){
    f32x4 v = *(const f32x4*)&wr[j];
    a0+=v[0]*cs[j]; a1+=v[1]*cs[j+1]; a2+=v[2]*cs[j+2]; a3+=v[3]*cs[j+3];
  }
  out[(long long)b*128 + t] = (a0+a1)+(a2+a3);
}

extern "C" void kernel_launch(void* const* d_in, const int* in_sizes, int n_in,
                              void* d_out, int out_size, void* d_ws, size_t ws_size,
                              hipStream_t stream)
{
  (void)in_sizes; (void)n_in; (void)out_size; (void)ws_size;
  const float* inputs = (const float*)d_in[0];
  const float* tstamp = (const float*)d_in[1];
  const float* emb    = (const float*)d_in[2];
  const float* Wall1w = (const float*)d_in[3];
  const float* Wall1b = (const float*)d_in[4];
  const float* Uall1w = (const float*)d_in[5];
  const float* Uall1b = (const float*)d_in[6];
  const float* Wd1w   = (const float*)d_in[7];
  const float* Wd1b   = (const float*)d_in[8];
  const float* Wall2w = (const float*)d_in[9];
  const float* Wall2b = (const float*)d_in[10];
  const float* Uall2w = (const float*)d_in[11];
  const float* Uall2b = (const float*)d_in[12];
  const float* Wd2w   = (const float*)d_in[13];
  const float* Wd2b   = (const float*)d_in[14];
  const float* wa     = (const float*)d_in[15];
  const float* Wbw    = (const float*)d_in[16];
  const float* Woutw  = (const float*)d_in[17];
  const float* h01    = (const float*)d_in[18];
  const float* c01    = (const float*)d_in[19];
  const float* h02    = (const float*)d_in[20];
  const float* c02    = (const float*)d_in[21];

  char* ws = (char*)d_ws;
  float* ux1   = (float*)(ws + 0);              // 104857600
  float* ux2   = (float*)(ws + 104857600LL);
  float* embF  = (float*)(ws + 209715200LL);    // 26214400
  u16*   embB  = (u16*)  (ws + 235929600LL);    // 13107200
  char*  scr   =          ws + 249036800LL;     // 72089600 region
  u16*   A0    = (u16*)scr;                     // 72089600 (dead after embed GEMM)
  u16*   out2  = (u16*)  (scr + 0);             // 13107200
  u16*   wpk   = (u16*)  (scr + 16777216LL);    // 1310720 (packed scan weights; inside dead A0 tail)
  float* alpha = (float*)(scr + 39321600LL);    // 102400
  float* ctx   = (float*)(scr + 39424000LL);    // 131072
  float* E4    = (float*)(scr + 39555072LL);    // 409600 (4 wave-partials x 128 b x 200 s)
  u16* embT    = (u16*)(ws + 321126400LL);      // 720896
  u16* Wall1B  = (u16*)(ws + 321847296LL);      // 524288
  u16* Wall2B  = (u16*)(ws + 322371584LL);
  u16* Uall1B  = (u16*)(ws + 322895872LL);
  u16* Uall2B  = (u16*)(ws + 323420160LL);
  u16* Wd1B    = (u16*)(ws + 323944448LL);      // 131072
  u16* Wd2B    = (u16*)(ws + 324075520LL);
  u16* WbB     = (u16*)(ws + 324206592LL);
  // total ws: ~324.3 MB (same layout envelope as passing rounds)

  // 1) all conversions (inputs, emb^T, 7 weights) in one launch
  k_prep<<<37824, 256, 0, stream>>>(inputs, A0, emb, embT,
                                    Wall1w, Wall2w, Uall1w, Uall2w, Wd1w, Wd2w, Wbw,
                                    Wall1B, Wall2B, Uall1B, Uall2B, Wd1B, Wd2B, WbB);
  // 2) embedded = inputs @ emb  (fp32 + bf16 copies; consumes A0)
  k_gemm<1><<<dim3(200,2), 256, 0, stream>>>(A0, embT, 256, 1408, embF, embB,
                                             nullptr, nullptr, nullptr, nullptr,
                                             nullptr, nullptr, nullptr, nullptr);
  // 3) pack scan weights into coalesced fragment layout (A0 now dead)
  k_wpack<<<320, 256, 0, stream>>>(Wall1B, Wd1B, Wall2B, Wd2B, wpk);
  // 4) ux1,ux2 = embedded @ Uall{1,2}^T + (Uall_b + Wall_b), one launch
  k_gemm<4><<<dim3(200,16), 256, 0, stream>>>(embB, Uall1B, 1024, 256, ux1, nullptr,
                                              Uall1b, Wall1b,
                                              Uall2B, ux2, Uall2b, Wall2b,
                                              nullptr, nullptr);
  // 5) zero ctx (atomic accumulation target)
  k_init<<<128, 256, 0, stream>>>(ctx);
  // 6) both TimeLSTM scans (8 WGs, batch-split, batched weight streaming)
  k_scan<<<8, 256, 0, stream>>>(wpk,
                                Wd1b, ux1, h01, c01,
                                Wd2b, ux2, h02, c02,
                                tstamp, wa, E4, out2);
  // 7) alpha = softmax(sum of E4 partials)
  k_attn<<<128, 256, 0, stream>>>(E4, alpha);
  // 8) ctx += sum_s emb * tanh(out2 @ Wb^T) * alpha  (fused, no P buffer)
  k_gemm<5><<<dim3(200,2), 256, 0, stream>>>(out2, WbB, 256, 256, ctx, nullptr,
                                             nullptr, nullptr, nullptr, nullptr,
                                             nullptr, nullptr, embF, alpha);
  // 9) out = ctx @ Wout^T
  k_out<<<128, 128, 0, stream>>>(ctx, Woutw, (float*)d_out);
}

// Round 7
// 1535.690 us; speedup vs baseline: 5.6165x; 5.6165x over previous
//
#include <hip/hip_runtime.h>

typedef unsigned short u16;
typedef unsigned int u32;
typedef unsigned long long u64;
typedef __attribute__((ext_vector_type(8))) short bf16x8;
typedef __attribute__((ext_vector_type(4))) float f32x4;
typedef __attribute__((ext_vector_type(4))) unsigned short us4;

#define MFMA(a,b,c) __builtin_amdgcn_mfma_f32_16x16x32_bf16((a),(b),(c),0,0,0)
#define KEEP(x) asm volatile("" : "+v"(x))

// B=128, SEQ=200, VOCAB=1400 (pad 1408), D=H=256, 4H=1024, NCLS=128, M=B*SEQ=25600

static __device__ __forceinline__ u16 f2b(float f){
  unsigned u = __float_as_uint(f);
  u += 0x7fffu + ((u >> 16) & 1u);          // RNE fp32 -> bf16
  return (u16)(u >> 16);
}
static __device__ __forceinline__ float sigm(float x){ return 1.0f/(1.0f+__expf(-x)); }
static __device__ __forceinline__ float tanhx(float x){
  x = fminf(fmaxf(x, -15.f), 15.f);
  float e = __expf(-2.f*x);
  return (1.f - e)/(1.f + e);
}
static __device__ __forceinline__ void gl16(const void* g, void* l){
  __builtin_amdgcn_global_load_lds((const __attribute__((address_space(1))) void*)g,
                                   (__attribute__((address_space(3))) void*)l, 16, 0, 0);
}

// ---------------- fused prep: inputs cvt + emb transpose-cvt + weights ----
__global__ __launch_bounds__(256) void k_prep(
  const float* __restrict__ in0, u16* __restrict__ A0,
  const float* __restrict__ emb, u16* __restrict__ embT,
  const float* __restrict__ s0, const float* __restrict__ s1, const float* __restrict__ s2,
  const float* __restrict__ s3, const float* __restrict__ s4, const float* __restrict__ s5,
  const float* __restrict__ s6,
  u16* __restrict__ d0, u16* __restrict__ d1, u16* __restrict__ d2, u16* __restrict__ d3,
  u16* __restrict__ d4, u16* __restrict__ d5, u16* __restrict__ d6)
{
  int bx = blockIdx.x, tid = threadIdx.x;
  if (bx < 35200){                     // inputs [25600 x 1400] -> bf16 padded 1408
    long long i4 = (long long)bx*256 + tid;      // < 9011200 exactly
    long long o = i4*4;
    int r = (int)(o / 1408);
    int c = (int)(o % 1408);
    us4 d;
    if (c + 4 <= 1400){
      f32x4 v = *(const f32x4*)&in0[(long long)r*1400 + c];
      d[0]=f2b(v[0]); d[1]=f2b(v[1]); d[2]=f2b(v[2]); d[3]=f2b(v[3]);
    } else {
      for (int k=0;k<4;k++){ int cc=c+k; d[k] = (cc<1400)? f2b(in0[(long long)r*1400+cc]) : (u16)0; }
    }
    *(us4*)&A0[(long long)r*1408 + c] = d;
  } else if (bx < 36608){              // emb [1400x256] -> embT [256x1408] bf16
    int idx = (bx-35200)*256 + tid;    // < 360448 exactly
    int n = idx / 1408, k = idx % 1408;
    embT[idx] = (k < 1400) ? f2b(emb[(long long)k*256 + n]) : (u16)0;
  } else {                             // 7 weight arrays fp32 -> bf16
    long long q = (long long)(bx-36608)*256 + tid;   // < 311296 exactly
    const float* src; u16* dst; long long rel;
    if      (q < 65536)  { src=s0; dst=d0; rel=q; }
    else if (q < 131072) { src=s1; dst=d1; rel=q-65536; }
    else if (q < 196608) { src=s2; dst=d2; rel=q-131072; }
    else if (q < 262144) { src=s3; dst=d3; rel=q-196608; }
    else if (q < 278528) { src=s4; dst=d4; rel=q-262144; }
    else if (q < 294912) { src=s5; dst=d5; rel=q-278528; }
    else                 { src=s6; dst=d6; rel=q-294912; }
    long long o = rel*4;
    f32x4 v = *(const f32x4*)&src[o];
    us4 d; d[0]=f2b(v[0]); d[1]=f2b(v[1]); d[2]=f2b(v[2]); d[3]=f2b(v[3]);
    *(us4*)&dst[o] = d;
  }
}

// ---------------- init: zero E + ctx + wave-flags ------------------------
__global__ __launch_bounds__(256) void k_init(float* __restrict__ E, float* __restrict__ ctx,
                                              int* __restrict__ fl){
  int i = blockIdx.x*256 + threadIdx.x;     // 229*256 = 58624 exactly
  if (i < 25600) E[i] = 0.f;
  else if (i < 58368) ctx[i-25600] = 0.f;   // 32768
  else fl[i-58368] = 0;                     // 256 wave-flags (unsigned >= poll)
}

// ---------------- bf16 MFMA GEMM: C[M,N] = A[M,K] * Bt[N,K]^T -------------
// EPI 1: write fp32 + bf16 copies
// EPI 4: dual-output ux GEMM, +bias pair, fp32 (blockIdx.y>=8 -> second set)
// EPI 5: ctx[b,col] += emb[row,col]*tanh(acc)*alpha[row]  (LDS + global atomics)
template<int EPI>
__global__ __launch_bounds__(256) void k_gemm(const u16* __restrict__ A, const u16* __restrict__ Bt,
    int N, int K,
    float* __restrict__ Cf, u16* __restrict__ Cb,
    const float* __restrict__ bias1, const float* __restrict__ bias2,
    const u16* __restrict__ Bt2, float* __restrict__ Cf2,
    const float* __restrict__ bias3, const float* __restrict__ bias4,
    const float* __restrict__ emb, const float* __restrict__ alpha)
{
  __shared__ __align__(16) u16 As[128*64];
  __shared__ __align__(16) u16 Bs[128*64];
  __shared__ float red[2][128];
  const int tid = threadIdx.x;
  const int l = tid & 63, w = tid >> 6;
  const int quad = l >> 4, lb = l & 15;
  const int wr = w >> 1, wc = w & 1;
  const long long m0 = (long long)blockIdx.x * 128;
  int n0 = blockIdx.y * 128;
  if (EPI==4 && blockIdx.y >= 8){
    Bt = Bt2; Cf = Cf2; bias1 = bias3; bias2 = bias4; n0 = (blockIdx.y-8)*128;
  }

  f32x4 acc[4][4];
  #pragma unroll
  for (int i=0;i<4;i++)
    #pragma unroll
    for (int j=0;j<4;j++) acc[i][j] = (f32x4){0.f,0.f,0.f,0.f};

  for (int kk = 0; kk < K; kk += 64){
    #pragma unroll
    for (int it=0; it<4; ++it){      // 128x64 bf16 tile, XOR-swizzled 16B slots
      int slot = it*256 + tid;
      int m = slot >> 3;
      int q = (slot & 7) ^ (m & 7);
      gl16(A + (m0+m)*K + kk + q*8, &As[slot*8]);
    }
    #pragma unroll
    for (int it=0; it<4; ++it){
      int slot = it*256 + tid;
      int m = slot >> 3;
      int q = (slot & 7) ^ (m & 7);
      gl16(Bt + (long long)(n0+m)*K + kk + q*8, &Bs[slot*8]);
    }
    __syncthreads();
    #pragma unroll
    for (int ks=0; ks<2; ++ks){
      int kq = quad + ks*4;
      bf16x8 af[4], bfr[4];
      #pragma unroll
      for (int i=0;i<4;i++){ int m = wr*64 + i*16 + lb; af[i]  = *(const bf16x8*)&As[m*64 + ((kq ^ (m&7))*8)]; }
      #pragma unroll
      for (int j=0;j<4;j++){ int n = wc*64 + j*16 + lb; bfr[j] = *(const bf16x8*)&Bs[n*64 + ((kq ^ (n&7))*8)]; }
      #pragma unroll
      for (int i=0;i<4;i++)
        #pragma unroll
        for (int j=0;j<4;j++)
          acc[i][j] = MFMA(af[i], bfr[j], acc[i][j]);
    }
    __syncthreads();
  }

  if (EPI==5){
    const int b0 = (int)(m0 / 200);
    red[tid>>7][tid&127] = 0.f;
    __syncthreads();
    #pragma unroll
    for (int i=0;i<4;i++){
      #pragma unroll
      for (int j=0;j<4;j++){
        int col = wc*64 + j*16 + lb;          // 0..127 within n0 tile
        #pragma unroll
        for (int r=0;r<4;r++){
          long long row = m0 + wr*64 + i*16 + quad*4 + r;
          long long o = row*N + n0 + col;
          float v = emb[o] * tanhx(acc[i][j][r]) * alpha[row];
          atomicAdd(&red[(int)(row/200) - b0][col], v);
        }
      }
    }
    __syncthreads();
    int bl = tid >> 7, col = tid & 127;       // 256 threads cover [2][128]
    int bb = b0 + bl;
    if (bb < 128) atomicAdd(&Cf[bb*256 + n0 + col], red[bl][col]);
    return;
  }

  #pragma unroll
  for (int i=0;i<4;i++){
    #pragma unroll
    for (int j=0;j<4;j++){
      int col = n0 + wc*64 + j*16 + lb;
      #pragma unroll
      for (int r=0;r<4;r++){
        long long row = m0 + wr*64 + i*16 + quad*4 + r;
        long long o = row*N + col;
        float v = acc[i][j][r];
        if (EPI==1){ Cf[o]=v; Cb[o]=f2b(v); }
        else { Cf[o] = v + bias1[col] + bias2[col]; }   // EPI 4
      }
    }
  }
}

// ---------------- persistent TimeLSTM scan, BOTH lstms per WG -------------
// 32 WGs: jw = bi>>3 (j-quarter), bc = bi&7 (batch chunk of 16). Each WG
// runs BOTH independent lstm chains for its (bc, jw), phase-interleaved so
// each lstm's exchange latency hides behind the other's GEMV+elementwise.
// Mailbox/flag address space is IDENTICAL to the proven r4 layout: 16 grps,
// grpA = bc (lstm0), grpB = 8+bc (lstm1).
//
// Per-step schedule:
//  GEMV0 -> elem0 -> mailbox stores0
//  GEMV1 (stores0 acks ripen under it) -> vmcnt(0) [cheap] -> flag0
//  elem1 -> mailbox stores1 -> vmcnt(0) -> flag1
//  outputs E (lstm0) + out2 (lstm1): acks ripen under next step's phases
//  B1 raw barrier -> own LDS writes (all 4 buffers)
//  pollA (flags ~2k cy old -> usually ready) -> 6 loads A
//  pollB -> 6 loads B -> unpack A,B -> lgkmcnt(0) -> B2 raw barrier
// Same per-wave flag protocol, slot-parity double buffer, and induction
// argument as r4 (each grp's group of 4 WGs is the same physical WG set).
__global__ __launch_bounds__(256,1) void k_scan(
  const u16* __restrict__ Wall1, const u16* __restrict__ Wd1, const float* __restrict__ Wd1b,
  const float* __restrict__ ux1, const float* __restrict__ h01, const float* __restrict__ c01,
  const u16* __restrict__ Wall2, const u16* __restrict__ Wd2, const float* __restrict__ Wd2b,
  const float* __restrict__ ux2, const float* __restrict__ h02, const float* __restrict__ c02,
  const float* __restrict__ ts, const float* __restrict__ wa,
  float* __restrict__ E, u16* __restrict__ out2,
  u64* __restrict__ mb, int* __restrict__ fl)
{
  __shared__ __align__(16) u16 hb0[16][264];
  __shared__ __align__(16) u16 cb0[16][264];
  __shared__ __align__(16) u16 hb1[16][264];
  __shared__ __align__(16) u16 cb1[16][264];
  const int bi = blockIdx.x;
  const int jw = bi >> 3;              // j-quarter 0..3
  const int bc = bi & 7;               // batch chunk 0..7
  const int grpA = bc, grpB = 8 + bc;

  const int tid = threadIdx.x;
  const int l = tid & 63, w = tid >> 6;
  const int quad = l >> 4, lb = l & 15;
  const int bg = bc*16 + lb;            // lane's global batch
  const int jwave = jw*64 + w*16;       // wave's 16 output rows (per gate)
  const int jlane = jwave + quad*4;     // lane's 4 j rows (C-layout)

  // ---- one-time: weight fragments for BOTH lstms (A-frag: m=lb, k=quad*8)
  // (compiler streams what doesn't fit — r4 precedent: measured fine)
  bf16x8 wf0[4][8], wdf0[8], wf1[4][8], wdf1[8];
  #pragma unroll
  for (int g=0; g<4; ++g)
    #pragma unroll
    for (int kk=0; kk<8; ++kk){
      wf0[g][kk] = *(const bf16x8*)&Wall1[(long long)(g*256 + jwave + lb)*256 + kk*32 + quad*8];
      KEEP(wf0[g][kk]);
      wf1[g][kk] = *(const bf16x8*)&Wall2[(long long)(g*256 + jwave + lb)*256 + kk*32 + quad*8];
      KEEP(wf1[g][kk]);
    }
  #pragma unroll
  for (int kk=0; kk<8; ++kk){
    wdf0[kk] = *(const bf16x8*)&Wd1[(long long)(jwave + lb)*256 + kk*32 + quad*8];
    KEEP(wdf0[kk]);
    wdf1[kk] = *(const bf16x8*)&Wd2[(long long)(jwave + lb)*256 + kk*32 + quad*8];
    KEEP(wdf1[kk]);
  }

  f32x4 bcs0 = *(const f32x4*)&Wd1b[jlane];
  f32x4 bcs1 = *(const f32x4*)&Wd2b[jlane];
  f32x4 wav  = *(const f32x4*)&wa[jlane];
  f32x4 creg0 = *(const f32x4*)&c01[(long long)bg*256 + jlane];
  f32x4 creg1 = *(const f32x4*)&c02[(long long)bg*256 + jlane];

  // ---- init LDS h/c for both lstms (16 batches x full 256 j), bf16
  {
    const int bbi = tid >> 4, j0i = (tid & 15) * 16;
    #pragma unroll
    for (int kq=0; kq<4; ++kq){
      f32x4 hv0 = *(const f32x4*)&h01[(long long)(bc*16+bbi)*256 + j0i + kq*4];
      f32x4 cv0 = *(const f32x4*)&c01[(long long)(bc*16+bbi)*256 + j0i + kq*4];
      f32x4 hv1 = *(const f32x4*)&h02[(long long)(bc*16+bbi)*256 + j0i + kq*4];
      f32x4 cv1 = *(const f32x4*)&c02[(long long)(bc*16+bbi)*256 + j0i + kq*4];
      us4 a, b, c, d;
      #pragma unroll
      for (int r=0;r<4;++r){ a[r]=f2b(hv0[r]); b[r]=f2b(cv0[r]); c[r]=f2b(hv1[r]); d[r]=f2b(cv1[r]); }
      *(us4*)&hb0[bbi][j0i+kq*4] = a;
      *(us4*)&cb0[bbi][j0i+kq*4] = b;
      *(us4*)&hb1[bbi][j0i+kq*4] = c;
      *(us4*)&cb1[bbi][j0i+kq*4] = d;
    }
  }
  __syncthreads();

  f32x4 uxr0[4], uxr1[4];
  #pragma unroll
  for (int g=0; g<4; ++g){
    uxr0[g] = *(const f32x4*)&ux1[(long long)bg*200*1024 + g*256 + jlane];
    uxr1[g] = *(const f32x4*)&ux2[(long long)bg*200*1024 + g*256 + jlane];
  }
  float tcur = ts[(long long)bg*200];

  for (int s=0; s<200; ++s){
    const int slot = (s+1)&1;
    const float tnow = tcur;

    // ======== lstm0 phase ========
    f32x4 ag0[4];
    #pragma unroll
    for (int g=0; g<4; ++g) ag0[g] = uxr0[g];
    if (s < 199){
      #pragma unroll
      for (int g=0; g<4; ++g)
        uxr0[g] = *(const f32x4*)&ux1[((long long)bg*200 + s+1)*1024 + g*256 + jlane];
    }
    f32x4 ad0 = bcs0;
    #pragma unroll
    for (int kk=0;kk<8;++kk){
      bf16x8 cf = *(const bf16x8*)&cb0[lb][kk*32 + quad*8];
      ad0 = MFMA(wdf0[kk], cf, ad0);
    }
    #pragma unroll
    for (int kk=0;kk<8;++kk){
      bf16x8 hf = *(const bf16x8*)&hb0[lb][kk*32 + quad*8];
      #pragma unroll
      for (int g=0; g<4; ++g) ag0[g] = MFMA(wf0[g][kk], hf, ag0[g]);
    }
    f32x4 hn0; us4 hp0, cp0;
    #pragma unroll
    for (int r=0;r<4;++r){
      float cs1 = tanhx(ad0[r]);
      float cadj = creg0[r] + cs1*(tnow - 1.0f);
      float fg = sigm(ag0[0][r]);
      float ig = sigm(ag0[1][r]);
      float og = sigm(ag0[2][r]);
      float cg = sigm(ag0[3][r]);
      float cn = fg*cadj + ig*cg;
      float hv = og*tanhx(cn);
      creg0[r]=cn; hn0[r]=hv;
      hp0[r]=f2b(hv); cp0[r]=f2b(cn);
    }
    // mailbox stores lstm0 (acks ripen under lstm1's GEMV)
    if (s < 199){
      long long xb = ((long long)((((slot*16+grpA)*4 + jw)*4 + w)))*128 + l*2;
      u64 w0 = (u64)((u32)hp0[0] | ((u32)cp0[0]<<16)) | ((u64)((u32)hp0[1] | ((u32)cp0[1]<<16))<<32);
      u64 w1 = (u64)((u32)hp0[2] | ((u32)cp0[2]<<16)) | ((u64)((u32)hp0[3] | ((u32)cp0[3]<<16))<<32);
      __hip_atomic_store(&mb[xb],   w0, __ATOMIC_RELAXED, __HIP_MEMORY_SCOPE_AGENT);
      __hip_atomic_store(&mb[xb+1], w1, __ATOMIC_RELAXED, __HIP_MEMORY_SCOPE_AGENT);
    }

    // ======== lstm1 phase ========
    f32x4 ag1[4];
    #pragma unroll
    for (int g=0; g<4; ++g) ag1[g] = uxr1[g];
    if (s < 199){
      #pragma unroll
      for (int g=0; g<4; ++g)
        uxr1[g] = *(const f32x4*)&ux2[((long long)bg*200 + s+1)*1024 + g*256 + jlane];
      tcur = ts[(long long)bg*200 + s+1];
    }
    f32x4 ad1 = bcs1;
    #pragma unroll
    for (int kk=0;kk<8;++kk){
      bf16x8 cf = *(const bf16x8*)&cb1[lb][kk*32 + quad*8];
      ad1 = MFMA(wdf1[kk], cf, ad1);
    }
    #pragma unroll
    for (int kk=0;kk<8;++kk){
      bf16x8 hf = *(const bf16x8*)&hb1[lb][kk*32 + quad*8];
      #pragma unroll
      for (int g=0; g<4; ++g) ag1[g] = MFMA(wf1[g][kk], hf, ag1[g]);
    }
    // publish flag0 now: stores0 acked during the GEMV above -> cheap drain
    if (s < 199){
      asm volatile("s_waitcnt vmcnt(0)" ::: "memory");
      if (l == 0)
        __hip_atomic_store(&fl[(grpA*4 + jw)*4 + w], s+1, __ATOMIC_RELAXED, __HIP_MEMORY_SCOPE_AGENT);
    }
    f32x4 hn1; us4 hp1, cp1;
    #pragma unroll
    for (int r=0;r<4;++r){
      float cs1 = tanhx(ad1[r]);
      float cadj = creg1[r] + cs1*(tnow - 1.0f);
      float fg = sigm(ag1[0][r]);
      float ig = sigm(ag1[1][r]);
      float og = sigm(ag1[2][r]);
      float cg = sigm(ag1[3][r]);
      float cn = fg*cadj + ig*cg;
      float hv = og*tanhx(cn);
      creg1[r]=cn; hn1[r]=hv;
      hp1[r]=f2b(hv); cp1[r]=f2b(cn);
    }
    if (s < 199){
      long long xb = ((long long)((((slot*16+grpB)*4 + jw)*4 + w)))*128 + l*2;
      u64 w0 = (u64)((u32)hp1[0] | ((u32)cp1[0]<<16)) | ((u64)((u32)hp1[1] | ((u32)cp1[1]<<16))<<32);
      u64 w1 = (u64)((u32)hp1[2] | ((u32)cp1[2]<<16)) | ((u64)((u32)hp1[3] | ((u32)cp1[3]<<16))<<32);
      __hip_atomic_store(&mb[xb],   w0, __ATOMIC_RELAXED, __HIP_MEMORY_SCOPE_AGENT);
      __hip_atomic_store(&mb[xb+1], w1, __ATOMIC_RELAXED, __HIP_MEMORY_SCOPE_AGENT);
      asm volatile("s_waitcnt vmcnt(0)" ::: "memory");
      if (l == 0)
        __hip_atomic_store(&fl[(grpB*4 + jw)*4 + w], s+1, __ATOMIC_RELAXED, __HIP_MEMORY_SCOPE_AGENT);
    }

    // outputs for step s (acks ripen under next step's phases)
    {
      float e = hn0[0]*wav[0] + hn0[1]*wav[1] + hn0[2]*wav[2] + hn0[3]*wav[3];
      e += __shfl_xor(e, 16, 64);
      e += __shfl_xor(e, 32, 64);
      if (l < 16) atomicAdd(&E[(long long)bg*200 + s], e);
      *(us4*)&out2[((long long)bg*200 + s)*256 + jlane] = hp1;
    }

    // ======== exchange/refill both lstms ========
    if (s < 199){
      // B1: all waves' GEMV LDS reads (both lstms) complete before overwrites
      asm volatile("" ::: "memory");
      __builtin_amdgcn_s_barrier();
      asm volatile("" ::: "memory");
      // own quarters -> LDS
      *(us4*)&hb0[lb][jlane] = hp0;
      *(us4*)&cb0[lb][jlane] = cp0;
      *(us4*)&hb1[lb][jlane] = hp1;
      *(us4*)&cb1[lb][jlane] = cp1;
      const u32 tgt = (u32)(s+1);
      const int sj = (jw + 1 + l) & 3;
      // poll lstm0 sibling flags (published ~a full phase ago)
      {
        const int* fp = &fl[(grpA*4 + sj)*4 + w];
        for (;;){
          u32 fv = tgt;
          if (l < 3) fv = (u32)__hip_atomic_load(fp, __ATOMIC_RELAXED, __HIP_MEMORY_SCOPE_AGENT);
          if (__all((int)(fv >= tgt))) break;
        }
      }
      u64 d0a, d0b, d1a, d1b, d2a, d2b;
      {
        const int j1 = (jw+1)&3, j2 = (jw+2)&3, j3 = (jw+3)&3;
        long long rb1 = ((long long)((((slot*16+grpA)*4 + j1)*4 + w)))*128 + l*2;
        long long rb2 = ((long long)((((slot*16+grpA)*4 + j2)*4 + w)))*128 + l*2;
        long long rb3 = ((long long)((((slot*16+grpA)*4 + j3)*4 + w)))*128 + l*2;
        d0a = __hip_atomic_load(&mb[rb1],   __ATOMIC_RELAXED, __HIP_MEMORY_SCOPE_AGENT);
        d0b = __hip_atomic_load(&mb[rb1+1], __ATOMIC_RELAXED, __HIP_MEMORY_SCOPE_AGENT);
        d1a = __hip_atomic_load(&mb[rb2],   __ATOMIC_RELAXED, __HIP_MEMORY_SCOPE_AGENT);
        d1b = __hip_atomic_load(&mb[rb2+1], __ATOMIC_RELAXED, __HIP_MEMORY_SCOPE_AGENT);
        d2a = __hip_atomic_load(&mb[rb3],   __ATOMIC_RELAXED, __HIP_MEMORY_SCOPE_AGENT);
        d2b = __hip_atomic_load(&mb[rb3+1], __ATOMIC_RELAXED, __HIP_MEMORY_SCOPE_AGENT);
      }
      // poll lstm1 sibling flags (lstm0 loads complete while this resolves)
      {
        const int* fp = &fl[(grpB*4 + sj)*4 + w];
        for (;;){
          u32 fv = tgt;
          if (l < 3) fv = (u32)__hip_atomic_load(fp, __ATOMIC_RELAXED, __HIP_MEMORY_SCOPE_AGENT);
          if (__all((int)(fv >= tgt))) break;
        }
      }
      u64 e0a, e0b, e1a, e1b, e2a, e2b;
      {
        const int j1 = (jw+1)&3, j2 = (jw+2)&3, j3 = (jw+3)&3;
        long long rb1 = ((long long)((((slot*16+grpB)*4 + j1)*4 + w)))*128 + l*2;
        long long rb2 = ((long long)((((slot*16+grpB)*4 + j2)*4 + w)))*128 + l*2;
        long long rb3 = ((long long)((((slot*16+grpB)*4 + j3)*4 + w)))*128 + l*2;
        e0a = __hip_atomic_load(&mb[rb1],   __ATOMIC_RELAXED, __HIP_MEMORY_SCOPE_AGENT);
        e0b = __hip_atomic_load(&mb[rb1+1], __ATOMIC_RELAXED, __HIP_MEMORY_SCOPE_AGENT);
        e1a = __hip_atomic_load(&mb[rb2],   __ATOMIC_RELAXED, __HIP_MEMORY_SCOPE_AGENT);
        e1b = __hip_atomic_load(&mb[rb2+1], __ATOMIC_RELAXED, __HIP_MEMORY_SCOPE_AGENT);
        e2a = __hip_atomic_load(&mb[rb3],   __ATOMIC_RELAXED, __HIP_MEMORY_SCOPE_AGENT);
        e2b = __hip_atomic_load(&mb[rb3+1], __ATOMIC_RELAXED, __HIP_MEMORY_SCOPE_AGENT);
      }
      // unpack lstm0 -> hb0/cb0 sibling quarters
      {
        const int j1 = (jw+1)&3, j2 = (jw+2)&3, j3 = (jw+3)&3;
        const int rc = w*16 + quad*4;
        us4 hh, cc; u32 lo, hi;
        lo=(u32)d0a; hi=(u32)(d0a>>32); hh[0]=(u16)lo; cc[0]=(u16)(lo>>16); hh[1]=(u16)hi; cc[1]=(u16)(hi>>16);
        lo=(u32)d0b; hi=(u32)(d0b>>32); hh[2]=(u16)lo; cc[2]=(u16)(lo>>16); hh[3]=(u16)hi; cc[3]=(u16)(hi>>16);
        *(us4*)&hb0[lb][j1*64 + rc] = hh;
        *(us4*)&cb0[lb][j1*64 + rc] = cc;
        lo=(u32)d1a; hi=(u32)(d1a>>32); hh[0]=(u16)lo; cc[0]=(u16)(lo>>16); hh[1]=(u16)hi; cc[1]=(u16)(hi>>16);
        lo=(u32)d1b; hi=(u32)(d1b>>32); hh[2]=(u16)lo; cc[2]=(u16)(lo>>16); hh[3]=(u16)hi; cc[3]=(u16)(hi>>16);
        *(us4*)&hb0[lb][j2*64 + rc] = hh;
        *(us4*)&cb0[lb][j2*64 + rc] = cc;
        lo=(u32)d2a; hi=(u32)(d2a>>32); hh[0]=(u16)lo; cc[0]=(u16)(lo>>16); hh[1]=(u16)hi; cc[1]=(u16)(hi>>16);
        lo=(u32)d2b; hi=(u32)(d2b>>32); hh[2]=(u16)lo; cc[2]=(u16)(lo>>16); hh[3]=(u16)hi; cc[3]=(u16)(hi>>16);
        *(us4*)&hb0[lb][j3*64 + rc] = hh;
        *(us4*)&cb0[lb][j3*64 + rc] = cc;
      }
      // unpack lstm1 -> hb1/cb1 sibling quarters
      {
        const int j1 = (jw+1)&3, j2 = (jw+2)&3, j3 = (jw+3)&3;
        const int rc = w*16 + quad*4;
        us4 hh, cc; u32 lo, hi;
        lo=(u32)e0a; hi=(u32)(e0a>>32); hh[0]=(u16)lo; cc[0]=(u16)(lo>>16); hh[1]=(u16)hi; cc[1]=(u16)(hi>>16);
        lo=(u32)e0b; hi=(u32)(e0b>>32); hh[2]=(u16)lo; cc[2]=(u16)(lo>>16); hh[3]=(u16)hi; cc[3]=(u16)(hi>>16);
        *(us4*)&hb1[lb][j1*64 + rc] = hh;
        *(us4*)&cb1[lb][j1*64 + rc] = cc;
        lo=(u32)e1a; hi=(u32)(e1a>>32); hh[0]=(u16)lo; cc[0]=(u16)(lo>>16); hh[1]=(u16)hi; cc[1]=(u16)(hi>>16);
        lo=(u32)e1b; hi=(u32)(e1b>>32); hh[2]=(u16)lo; cc[2]=(u16)(lo>>16); hh[3]=(u16)hi; cc[3]=(u16)(hi>>16);
        *(us4*)&hb1[lb][j2*64 + rc] = hh;
        *(us4*)&cb1[lb][j2*64 + rc] = cc;
        lo=(u32)e2a; hi=(u32)(e2a>>32); hh[0]=(u16)lo; cc[0]=(u16)(lo>>16); hh[1]=(u16)hi; cc[1]=(u16)(hi>>16);
        lo=(u32)e2b; hi=(u32)(e2b>>32); hh[2]=(u16)lo; cc[2]=(u16)(lo>>16); hh[3]=(u16)hi; cc[3]=(u16)(hi>>16);
        *(us4*)&hb1[lb][j3*64 + rc] = hh;
        *(us4*)&cb1[lb][j3*64 + rc] = cc;
      }
      // B2: all LDS h/c(s+1) writes complete; lgkm only, vmem stays in flight
      asm volatile("s_waitcnt lgkmcnt(0)" ::: "memory");
      __builtin_amdgcn_sched_barrier(0);
      __builtin_amdgcn_s_barrier();
      asm volatile("" ::: "memory");
    }
  }
}

// ---------------- softmax over precomputed E -> alpha ----------------
__global__ __launch_bounds__(256) void k_attn(const float* __restrict__ E, float* __restrict__ alpha){
  __shared__ float buf[256];
  int b = blockIdx.x, tid = threadIdx.x;
  float Ev = (tid < 200) ? E[(long long)b*200 + tid] : -1e30f;
  buf[tid]=Ev; __syncthreads();
  for (int st=128; st>0; st>>=1){ if (tid<st) buf[tid]=fmaxf(buf[tid],buf[tid+st]); __syncthreads(); }
  float mx = buf[0]; __syncthreads();
  float e = (tid<200)? __expf(Ev-mx) : 0.f;
  buf[tid]=e; __syncthreads();
  for (int st=128; st>0; st>>=1){ if (tid<st) buf[tid]+=buf[tid+st]; __syncthreads(); }
  float sm = buf[0];
  if (tid<200) alpha[(long long)b*200+tid] = e/sm;
}

// ---------------- out = ctx @ Wout^T ----------------
__global__ __launch_bounds__(128) void k_out(const float* __restrict__ ctx, const float* __restrict__ Wout,
                                             float* __restrict__ out){
  __shared__ float cs[256];
  int b = blockIdx.x, t = threadIdx.x;
  cs[t] = ctx[b*256+t]; cs[t+128] = ctx[b*256+t+128];
  __syncthreads();
  const float* wr = Wout + (long long)t*256;
  float a0=0,a1=0,a2=0,a3=0;
  for (int j=0;j<256;j+=4){
    f32x4 v = *(const f32x4*)&wr[j];
    a0+=v[0]*cs[j]; a1+=v[1]*cs[j+1]; a2+=v[2]*cs[j+2]; a3+=v[3]*cs[j+3];
  }
  out[(long long)b*128 + t] = (a0+a1)+(a2+a3);
}

extern "C" void kernel_launch(void* const* d_in, const int* in_sizes, int n_in,
                              void* d_out, int out_size, void* d_ws, size_t ws_size,
                              hipStream_t stream)
{
  (void)in_sizes; (void)n_in; (void)out_size; (void)ws_size;
  const float* inputs = (const float*)d_in[0];
  const float* tstamp = (const float*)d_in[1];
  const float* emb    = (const float*)d_in[2];
  const float* Wall1w = (const float*)d_in[3];
  const float* Wall1b = (const float*)d_in[4];
  const float* Uall1w = (const float*)d_in[5];
  const float* Uall1b = (const float*)d_in[6];
  const float* Wd1w   = (const float*)d_in[7];
  const float* Wd1b   = (const float*)d_in[8];
  const float* Wall2w = (const float*)d_in[9];
  const float* Wall2b = (const float*)d_in[10];
  const float* Uall2w = (const float*)d_in[11];
  const float* Uall2b = (const float*)d_in[12];
  const float* Wd2w   = (const float*)d_in[13];
  const float* Wd2b   = (const float*)d_in[14];
  const float* wa     = (const float*)d_in[15];
  const float* Wbw    = (const float*)d_in[16];
  const float* Woutw  = (const float*)d_in[17];
  const float* h01    = (const float*)d_in[18];
  const float* c01    = (const float*)d_in[19];
  const float* h02    = (const float*)d_in[20];
  const float* c02    = (const float*)d_in[21];

  char* ws = (char*)d_ws;
  float* ux1   = (float*)(ws + 0);              // 104857600
  float* ux2   = (float*)(ws + 104857600LL);
  float* embF  = (float*)(ws + 209715200LL);    // 26214400
  u16*   embB  = (u16*)  (ws + 235929600LL);    // 13107200
  char*  scr   =          ws + 249036800LL;     // 72089600 region
  u16*   A0    = (u16*)scr;                     // 72089600 (dead after embed GEMM)
  u16*   out2  = (u16*)  (scr + 0);             // 13107200
  float* alpha = (float*)(scr + 39321600LL);    // 102400
  float* ctx   = (float*)(scr + 39424000LL);    // 131072
  float* E     = (float*)(scr + 39555072LL);    // 102400
  u64*   mb    = (u64*)  (scr + 39657472LL);    // 524288 (2 slot x 16 grp x 4 jw x 4 w x 64 lane x 16B)
  int*   fl    = (int*)  (scr + 40181760LL);    // 1024 (256 wave-flags)
  u16* embT    = (u16*)(ws + 321126400LL);      // 720896
  u16* Wall1B  = (u16*)(ws + 321847296LL);      // 524288
  u16* Wall2B  = (u16*)(ws + 322371584LL);
  u16* Uall1B  = (u16*)(ws + 322895872LL);
  u16* Uall2B  = (u16*)(ws + 323420160LL);
  u16* Wd1B    = (u16*)(ws + 323944448LL);      // 131072
  u16* Wd2B    = (u16*)(ws + 324075520LL);
  u16* WbB     = (u16*)(ws + 324206592LL);
  // total ws: ~324.3 MB (same layout envelope as passing rounds)

  // 1) all conversions (inputs, emb^T, 7 weights) in one launch
  k_prep<<<37824, 256, 0, stream>>>(inputs, A0, emb, embT,
                                    Wall1w, Wall2w, Uall1w, Uall2w, Wd1w, Wd2w, Wbw,
                                    Wall1B, Wall2B, Uall1B, Uall2B, Wd1B, Wd2B, WbB);
  // 2) embedded = inputs @ emb  (fp32 + bf16 copies)
  k_gemm<1><<<dim3(200,2), 256, 0, stream>>>(A0, embT, 256, 1408, embF, embB,
                                             nullptr, nullptr, nullptr, nullptr,
                                             nullptr, nullptr, nullptr, nullptr);
  // 3) ux1,ux2 = embedded @ Uall{1,2}^T + (Uall_b + Wall_b), one launch
  k_gemm<4><<<dim3(200,16), 256, 0, stream>>>(embB, Uall1B, 1024, 256, ux1, nullptr,
                                              Uall1b, Wall1b,
                                              Uall2B, ux2, Uall2b, Wall2b,
                                              nullptr, nullptr);
  // 4) zero E + ctx + wave-flags (atomic/poll targets)
  k_init<<<229, 256, 0, stream>>>(E, ctx, fl);
  // 5) both TimeLSTM scans (32 persistent WGs, both lstms phase-interleaved)
  k_scan<<<32, 256, 0, stream>>>(Wall1B, Wd1B, Wd1b, ux1, h01, c01,
                                 Wall2B, Wd2B, Wd2b, ux2, h02, c02,
                                 tstamp, wa, E, out2, mb, fl);
  // 6) alpha = softmax(E)
  k_attn<<<128, 256, 0, stream>>>(E, alpha);
  // 7) ctx += sum_s emb * tanh(out2 @ Wb^T) * alpha  (fused, no P buffer)
  k_gemm<5><<<dim3(200,2), 256, 0, stream>>>(out2, WbB, 256, 256, ctx, nullptr,
                                             nullptr, nullptr, nullptr, nullptr,
                                             nullptr, nullptr, embF, alpha);
  // 8) out = ctx @ Wout^T
  k_out<<<128, 128, 0, stream>>>(ctx, Woutw, (float*)d_out);
}